// Round 1
// baseline (568.158 us; speedup 1.0000x reference)
//
#include <hip/hip_runtime.h>

#define HH 512
#define WW 512
#define NQ 128            // float4 quads per row
#define NT 198            // timesteps in the residual
#define RPB 8             // rows per block
#define NSTRIP (HH / RPB) // 64
#define NBLK (NSTRIP * NT)

// Block = 128 threads, one float4 quad per thread, rolling 5-row register
// window over an 8-row strip. Grid = (64 strips, 198 timesteps).
// Periodic wrap; row/col 0 double-counted (513-grid aliasing) -> weights.
// No same-address atomics (measured ~11.3 ns serialized each in R1/R2).
__global__ __launch_bounds__(128)
void pde_residual_kernel(const float* __restrict__ in, float2* __restrict__ partial) {
    const int t     = blockIdx.y;
    const int strip = blockIdx.x;
    const int q     = threadIdx.x;      // quad 0..127
    const int j0    = q * 4;
    const int i0    = strip * RPB;

    const size_t plane4 = (size_t)HH * NQ;
    const float4* __restrict__ U  = (const float4*)in + (size_t)(2 * t) * plane4;
    const float4* __restrict__ V  = U + plane4;
    const float4* __restrict__ Un = U + 2 * plane4;
    const float4* __restrict__ Vn = U + 3 * plane4;

    // rolling window: at iteration r, slots (r+s)%5 hold rows i0+r-2+s, s=0..4
    float4 wu[5], wv[5];
    #pragma unroll
    for (int s = 0; s < 5; ++s) {
        const int rq = ((i0 - 2 + s) & (HH - 1)) * NQ;
        wu[s] = U[rq + q];
        wv[s] = V[rq + q];
    }

    // horizontal halo columns (2 each side), 8B-aligned float2
    const int jl2 = ((j0 - 2) & (WW - 1)) >> 1;
    const int jr2 = ((j0 + 4) & (WW - 1)) >> 1;

    float su = 0.0f, sv = 0.0f;

    #pragma unroll
    for (int r = 0; r < RPB; ++r) {
        const int rq = ((i0 + r) & (HH - 1)) * NQ;

        const float2* __restrict__ U2 = (const float2*)(U + rq);
        const float2* __restrict__ V2 = (const float2*)(V + rq);
        const float2 uLp = U2[jl2];
        const float2 uRp = U2[jr2];
        const float2 vLp = V2[jl2];
        const float2 vRp = V2[jr2];
        const float4 unC = Un[rq + q];
        const float4 vnC = Vn[rq + q];

        // prefetch next window row (row i0+r+3) before compute
        float4 nu, nv;
        if (r < RPB - 1) {
            const int nrq = ((i0 + r + 3) & (HH - 1)) * NQ;
            nu = U[nrq + q];
            nv = V[nrq + q];
        }

        const float4 um2 = wu[(r + 0) % 5], vm2 = wv[(r + 0) % 5];
        const float4 um1 = wu[(r + 1) % 5], vm1 = wv[(r + 1) % 5];
        const float4 uc4 = wu[(r + 2) % 5], vc4 = wv[(r + 2) % 5];
        const float4 up1 = wu[(r + 3) % 5], vp1 = wv[(r + 3) % 5];
        const float4 up2 = wu[(r + 4) % 5], vp2 = wv[(r + 4) % 5];

        // horizontal windows: hu[k+2] = u(i, j0+k)
        const float hu[8] = {uLp.x, uLp.y, uc4.x, uc4.y, uc4.z, uc4.w, uRp.x, uRp.y};
        const float hv[8] = {vLp.x, vLp.y, vc4.x, vc4.y, vc4.z, vc4.w, vRp.x, vRp.y};
        const float uN[4] = {um1.x + up1.x, um1.y + up1.y, um1.z + up1.z, um1.w + up1.w};
        const float uF[4] = {um2.x + up2.x, um2.y + up2.y, um2.z + up2.z, um2.w + up2.w};
        const float vN[4] = {vm1.x + vp1.x, vm1.y + vp1.y, vm1.z + vp1.z, vm1.w + vp1.w};
        const float vF[4] = {vm2.x + vp2.x, vm2.y + vp2.y, vm2.z + vp2.z, vm2.w + vp2.w};
        const float tuu[4] = {unC.x, unC.y, unC.z, unC.w};
        const float tvv[4] = {vnC.x, vnC.y, vnC.z, vnC.w};

        const float wi = (i0 + r == 0) ? 2.0f : 1.0f;

        #pragma unroll
        for (int k = 0; k < 4; ++k) {
            const float uc = hu[k + 2];
            const float vc = hv[k + 2];

            const float nearu = uN[k] + hu[k + 1] + hu[k + 3];
            const float faru  = uF[k] + hu[k] + hu[k + 4];
            const float nearv = vN[k] + hv[k + 1] + hv[k + 3];
            const float farv  = vF[k] + hv[k] + hv[k + 4];

            // lap = (-5*c + 4/3*near - 1/12*far) / DX^2, 1/DX^2 = 25
            const float lapu = (-5.0f * uc + (4.0f / 3.0f) * nearu - (1.0f / 12.0f) * faru) * 25.0f;
            const float lapv = (-5.0f * vc + (4.0f / 3.0f) * nearv - (1.0f / 12.0f) * farv) * 25.0f;

            const float ut = (tuu[k] - uc) * 80.0f;   // 1/DT
            const float vt = (tvv[k] - vc) * 80.0f;

            const float s  = uc * uc + vc * vc;
            const float fu = ut - (0.1f * lapu + (1.0f - s) * uc + s * vc);
            const float fv = vt - (0.1f * lapv + (1.0f - s) * vc - s * uc);

            const float w = wi * ((j0 + k == 0) ? 2.0f : 1.0f);
            su += w * fu * fu;
            sv += w * fv * fv;
        }

        // rotate window: oldest slot takes row i0+r+3
        if (r < RPB - 1) {
            wu[r % 5] = nu;
            wv[r % 5] = nv;
        }
    }

    // wave shuffle reduction (64 lanes), then across the 2 waves via LDS
    #pragma unroll
    for (int off = 32; off > 0; off >>= 1) {
        su += __shfl_down(su, off);
        sv += __shfl_down(sv, off);
    }
    __shared__ float s_u[2], s_v[2];
    const int wave = threadIdx.x >> 6;
    if ((threadIdx.x & 63) == 0) { s_u[wave] = su; s_v[wave] = sv; }
    __syncthreads();
    if (threadIdx.x == 0) {
        partial[blockIdx.y * gridDim.x + blockIdx.x] =
            make_float2(s_u[0] + s_u[1], s_v[0] + s_v[1]);
    }
}

__global__ __launch_bounds__(1024)
void reduce_kernel(const float2* __restrict__ partial, float* __restrict__ out) {
    double su = 0.0, sv = 0.0;
    for (int idx = threadIdx.x; idx < NBLK; idx += 1024) {
        const float2 p = partial[idx];
        su += (double)p.x;
        sv += (double)p.y;
    }
    #pragma unroll
    for (int off = 32; off > 0; off >>= 1) {
        su += __shfl_down(su, off);
        sv += __shfl_down(sv, off);
    }
    __shared__ double d_u[16], d_v[16];
    const int wave = threadIdx.x >> 6;
    if ((threadIdx.x & 63) == 0) { d_u[wave] = su; d_v[wave] = sv; }
    __syncthreads();
    if (threadIdx.x == 0) {
        double tu = 0.0, tv = 0.0;
        #pragma unroll
        for (int wv2 = 0; wv2 < 16; ++wv2) { tu += d_u[wv2]; tv += d_v[wv2]; }
        const double denom = (double)NT * 513.0 * 513.0;
        out[0] = (float)(tu / denom);
        out[1] = (float)(tv / denom);
    }
}

extern "C" void kernel_launch(void* const* d_in, const int* in_sizes, int n_in,
                              void* d_out, int out_size, void* d_ws, size_t ws_size,
                              hipStream_t stream) {
    const float* in = (const float*)d_in[0];
    float* out = (float*)d_out;
    float2* partial = (float2*)d_ws;   // NBLK float2 = ~101 KB, fully overwritten

    dim3 grid(NSTRIP, NT);
    pde_residual_kernel<<<grid, 128, 0, stream>>>(in, partial);
    reduce_kernel<<<1, 1024, 0, stream>>>(partial, out);
}